// Round 16
// baseline (189.931 us; speedup 1.0000x reference)
//
#include <hip/hip_runtime.h>
#include <math.h>

static constexpr int NNODE = 4096;
static constexpr int HDIM  = 256;
static constexpr int DIN   = 128;
static constexpr int HEADS = 8;
static constexpr int SPLIT = 4;     // attention key-split

using short8 = __attribute__((ext_vector_type(8))) short;
using f32x4  = __attribute__((ext_vector_type(4))) float;

__device__ inline unsigned short bfr(float x) {   // RNE fp32->bf16
    union { float f; unsigned u; } v; v.f = x;
    unsigned r = v.u + 0x7FFFu + ((v.u >> 16) & 1u);
    return (unsigned short)(r >> 16);
}
__device__ inline float bf2f(unsigned short u) {
    union { unsigned u; float f; } v; v.u = (unsigned)u << 16; return v.f;
}
__device__ inline float bf2f_lo(unsigned u) {
    union { unsigned u; float f; } v; v.u = u << 16; return v.f;
}
__device__ inline float bf2f_hi(unsigned u) {
    union { unsigned u; float f; } v; v.u = u & 0xFFFF0000u; return v.f;
}
__device__ inline unsigned cvt_pk_bf16(float lo, float hi) {
    unsigned r;
    asm("v_cvt_pk_bf16_f32 %0, %1, %2" : "=v"(r) : "v"(lo), "v"(hi));
    return r;
}
__device__ inline float ex2(float x) {            // bare v_exp_f32 (exp2)
    float r;
    asm("v_exp_f32 %0, %1" : "=v"(r) : "v"(x));
    return r;
}

// scale/sqrt(32) folded with log2(e): softmax computed in exp2 domain.
static constexpr float QSCALE_LOG2 = 0.25503527f;   // 0.176776695 * 1.442695041

// ---------------------------------------------------------------------------
__global__ __launch_bounds__(256) void k_scan_norm(const int* __restrict__ degi,
        int* __restrict__ off, int* __restrict__ cursor,
        float* __restrict__ dinv, float* __restrict__ invdeg) {
    __shared__ int partial[256];
    int t = threadIdx.x;
    int local[16];
    int s = 0;
    #pragma unroll
    for (int i = 0; i < 16; ++i) { local[i] = degi[t * 16 + i]; s += local[i]; }
    partial[t] = s;
    __syncthreads();
    #pragma unroll
    for (int d = 1; d < 256; d <<= 1) {
        int add = (t >= d) ? partial[t - d] : 0;
        __syncthreads();
        partial[t] += add;
        __syncthreads();
    }
    int b = partial[t] - s;
    #pragma unroll
    for (int i = 0; i < 16; ++i) {
        int n = t * 16 + i;
        off[n] = b; cursor[n] = b; b += local[i];
        float d = (float)local[i] + 1.0f;
        dinv[n]   = rsqrtf(d);
        invdeg[n] = 1.0f / d;
    }
}

__global__ void k_fill(const int* __restrict__ ei, int* __restrict__ cursor,
                       int* __restrict__ csr, int E) {
    int e = blockIdx.x * 256 + threadIdx.x;
    if (e < E) {
        int d = ei[E + e];
        int p = atomicAdd(&cursor[d], 1);
        csr[p] = ei[e];
    }
}

// ---------------------------------------------------------------------------
// weight + x prep (bf16 convert / transpose / concat) FUSED with degree count.
__global__ __launch_bounds__(256) void k_prep(
        const float* __restrict__ W1, const float* __restrict__ W2,
        const float* __restrict__ W3, const float* __restrict__ in_w,
        const float* __restrict__ outw, const float* __restrict__ fp1w,
        const float* __restrict__ pd1w, const float* __restrict__ fp1b,
        const float* __restrict__ pd1b, const float* __restrict__ x,
        const int* __restrict__ ei, int E, int* __restrict__ degi,
        unsigned short* __restrict__ W1t, unsigned short* __restrict__ W2t,
        unsigned short* __restrict__ W3t, unsigned short* __restrict__ in_wb,
        unsigned short* __restrict__ outwb, unsigned short* __restrict__ wcatb,
        float* __restrict__ bcat, unsigned short* __restrict__ xb) {
    int idx = blockIdx.x * 256 + threadIdx.x;
    if (idx < 32768) {                       // W1 [128][256] -> W1t [256][128]
        int c = idx >> 7, k = idx & 127;
        W1t[idx] = bfr(W1[(size_t)k * 256 + c]);
    } else if (idx < 98304) {                // W2 [256][256] -> W2t
        int j = idx - 32768; int c = j >> 8, k = j & 255;
        W2t[j] = bfr(W2[(size_t)k * 256 + c]);
    } else if (idx < 163840) {
        int j = idx - 98304; int c = j >> 8, k = j & 255;
        W3t[j] = bfr(W3[(size_t)k * 256 + c]);
    } else if (idx < 360448) {               // in_w already [768][256]
        int j = idx - 163840;
        in_wb[j] = bfr(in_w[j]);
    } else if (idx < 425984) {               // outw already [256][256]
        int j = idx - 360448;
        outwb[j] = bfr(outw[j]);
    } else if (idx < 491520) {               // wcat = [fp1w; pd1w]
        int j = idx - 425984;
        int row = j >> 8, k = j & 255;
        wcatb[j] = bfr(row < 128 ? fp1w[(size_t)row * 256 + k]
                                 : pd1w[(size_t)(row - 128) * 256 + k]);
        if (j < 256) bcat[j] = (j < 128) ? fp1b[j] : pd1b[j - 128];
    } else if (idx < 557056) {               // x -> bf16, 8 elems/thread
        int i = (idx - 491520) * 8;
        float4 a = *(const float4*)&x[i];
        float4 b = *(const float4*)&x[i + 4];
        short8 o;
        o[0]=(short)bfr(a.x); o[1]=(short)bfr(a.y); o[2]=(short)bfr(a.z); o[3]=(short)bfr(a.w);
        o[4]=(short)bfr(b.x); o[5]=(short)bfr(b.y); o[6]=(short)bfr(b.z); o[7]=(short)bfr(b.w);
        *(short8*)&xb[i] = o;
    } else if (idx < 557056 + E) {           // degree count (degi pre-zeroed)
        atomicAdd(&degi[ei[E + (idx - 557056)]], 1);
    }
}

// ---------------------------------------------------------------------------
// wave-per-node CSR gather (norm only; bias/relu moved to the GEMM epilogue,
// valid by GCN linearity: agg(norm*(x@W)) = (agg(norm*x))@W).
// CHL = channels per lane (2 for 128-dim, 4 for 256-dim). No LDS, no barriers.
template<int CHL>
__global__ __launch_bounds__(256) void k_gather2(const unsigned short* __restrict__ hW,
        const int* __restrict__ csr, const int* __restrict__ off,
        const int* __restrict__ degi, const float* __restrict__ dinv,
        const float* __restrict__ invdeg, unsigned short* __restrict__ aggb) {
    constexpr int CH = 64 * CHL;
    const int wave = threadIdx.x >> 6, lane = threadIdx.x & 63;
    const int n = blockIdx.x * 4 + wave;
    const int start = off[n];
    const int cnt = degi[n];
    float a0 = 0.f, a1 = 0.f, a2 = 0.f, a3 = 0.f;
    for (int k0 = 0; k0 < cnt; k0 += 64) {
        int myidx = 0; float myw = 0.f;
        if (k0 + lane < cnt) {
            myidx = csr[start + k0 + lane];
            myw = dinv[myidx];
        }
        int lim = min(64, cnt - k0);
        for (int k = 0; k < lim; ++k) {
            int s = __shfl(myidx, k);
            float wgt = __shfl(myw, k);
            if (CHL == 4) {
                uint2 hv = *(const uint2*)&hW[(size_t)s * CH + lane * 4];
                a0 += bf2f_lo(hv.x) * wgt;
                a1 += bf2f_hi(hv.x) * wgt;
                a2 += bf2f_lo(hv.y) * wgt;
                a3 += bf2f_hi(hv.y) * wgt;
            } else {
                unsigned hv = *(const unsigned*)&hW[(size_t)s * CH + lane * 2];
                a0 += bf2f_lo(hv) * wgt;
                a1 += bf2f_hi(hv) * wgt;
            }
        }
    }
    float dn = dinv[n], idg = invdeg[n];
    if (CHL == 4) {
        uint2 sv = *(const uint2*)&hW[(size_t)n * CH + lane * 4];
        float v0 = a0 * dn + bf2f_lo(sv.x) * idg;
        float v1 = a1 * dn + bf2f_hi(sv.x) * idg;
        float v2 = a2 * dn + bf2f_lo(sv.y) * idg;
        float v3 = a3 * dn + bf2f_hi(sv.y) * idg;
        uint2 pk;
        pk.x = cvt_pk_bf16(v0, v1);
        pk.y = cvt_pk_bf16(v2, v3);
        *(uint2*)&aggb[(size_t)n * CH + lane * 4] = pk;
    } else {
        unsigned sv = *(const unsigned*)&hW[(size_t)n * CH + lane * 2];
        float v0 = a0 * dn + bf2f_lo(sv) * idg;
        float v1 = a1 * dn + bf2f_hi(sv) * idg;
        *(unsigned*)&aggb[(size_t)n * CH + lane * 2] = cvt_pk_bf16(v0, v1);
    }
}

// ---------------------------------------------------------------------------
// bf16 MFMA GEMM: C[M=4096][Nout] = A_bf16 @ B_bf16^T (+bias) (+addsrc)
// EPI: 0 fp32(+bias), 1 bf16(+bias)(+add), 2 qkv, 3 bf16 relu(v+bias),
//      4 dual: bf16 (P0) + fp32 (P1), v+bias.
template<int K, int EPI, bool BIAS, bool ADD>
__global__ __launch_bounds__(256) void k_bgemm(
        const unsigned short* __restrict__ A, const unsigned short* __restrict__ B,
        const float* __restrict__ bias, const float* __restrict__ addsrc,
        void* __restrict__ P0, void* __restrict__ P1, void* __restrict__ P2,
        int Nout) {
    const int lane = threadIdx.x & 63, wave = threadIdx.x >> 6;
    const int ql = lane & 15, g = lane >> 4;
    const int m0w = blockIdx.y * 64 + wave * 16;
    const int n0 = blockIdx.x * 32;
    const unsigned short* ap = A + (size_t)(m0w + ql) * K + g * 8;
    const unsigned short* bp = B + (size_t)(n0 + ql) * K + g * 8;

    f32x4 acc[2] = {{0,0,0,0},{0,0,0,0}};
    #pragma unroll
    for (int k0 = 0; k0 < K; k0 += 32) {
        short8 a = *(const short8*)(ap + k0);
        #pragma unroll
        for (int nt = 0; nt < 2; ++nt) {
            short8 b = *(const short8*)(bp + (size_t)nt * 16 * K + k0);
            acc[nt] = __builtin_amdgcn_mfma_f32_16x16x32_bf16(a, b, acc[nt], 0, 0, 0);
        }
    }
    #pragma unroll
    for (int nt = 0; nt < 2; ++nt) {
        const int col = n0 + nt * 16 + ql;
        const float bv = BIAS ? bias[col] : 0.f;
        if (EPI == 2) {
            const int sec = col >> 8, cc = col & 255;
            const int head = cc >> 5, dh = cc & 31;
            if (sec == 2) {
                unsigned short* dst = (unsigned short*)P2
                    + ((size_t)head * 32 + dh) * NNODE + m0w + g * 4;
                uint2 pk;
                pk.x = cvt_pk_bf16(acc[nt][0] + bv, acc[nt][1] + bv);
                pk.y = cvt_pk_bf16(acc[nt][2] + bv, acc[nt][3] + bv);
                *(uint2*)dst = pk;
            } else {
                unsigned short* dst = (unsigned short*)(sec == 0 ? P0 : P1);
                const float sc = (sec == 0) ? QSCALE_LOG2 : 1.0f;
                #pragma unroll
                for (int i = 0; i < 4; ++i) {
                    int row = m0w + g * 4 + i;
                    dst[((size_t)head * NNODE + row) * 32 + dh] = bfr((acc[nt][i] + bv) * sc);
                }
            }
        } else if (EPI == 1 || EPI == 3) {
            unsigned short* Cb = (unsigned short*)P0;
            #pragma unroll
            for (int i = 0; i < 4; ++i) {
                int row = m0w + g * 4 + i;
                float v = acc[nt][i] + bv;
                if (ADD) v += addsrc[(size_t)row * Nout + col];
                if (EPI == 3) v = fmaxf(v, 0.f);
                Cb[(size_t)row * Nout + col] = bfr(v);
            }
        } else if (EPI == 4) {
            unsigned short* Cb = (unsigned short*)P0;
            float* Cf = (float*)P1;
            #pragma unroll
            for (int i = 0; i < 4; ++i) {
                int row = m0w + g * 4 + i;
                float v = acc[nt][i] + bv;
                Cb[(size_t)row * Nout + col] = bfr(v);
                Cf[(size_t)row * Nout + col] = v;
            }
        } else {
            float* Cf = (float*)P0;
            #pragma unroll
            for (int i = 0; i < 4; ++i) {
                int row = m0w + g * 4 + i;
                float v = acc[nt][i] + bv;
                if (ADD) v += addsrc[(size_t)row * Nout + col];
                Cf[(size_t)row * Nout + col] = v;
            }
        }
    }
}

// ---------------------------------------------------------------------------
// out-proj GEMM with the split-K attention MERGE fused into the A-load.
__global__ __launch_bounds__(256) void k_bgemm_merge(
        const unsigned short* __restrict__ po, const float* __restrict__ pl,
        const unsigned short* __restrict__ B, const float* __restrict__ bias,
        const float* __restrict__ addsrc, unsigned short* __restrict__ Cb) {
    constexpr int K = HDIM;
    const int lane = threadIdx.x & 63, wave = threadIdx.x >> 6;
    const int ql = lane & 15, g = lane >> 4;
    const int m0w = blockIdx.y * 64 + wave * 16;
    const int n0 = blockIdx.x * 32;
    const int row = m0w + ql;
    const unsigned short* bp = B + (size_t)(n0 + ql) * K + g * 8;

    f32x4 acc[2] = {{0,0,0,0},{0,0,0,0}};
    #pragma unroll
    for (int k0 = 0; k0 < K; k0 += 32) {
        const int kidx = k0 + g * 8;          // 8 consecutive, same head
        const int hd = kidx >> 5, dh0 = kidx & 31;
        const size_t b4 = ((size_t)hd * NNODE + row) * SPLIT;
        float L = pl[b4] + pl[b4 + 1] + pl[b4 + 2] + pl[b4 + 3];
        float rcpL = 1.f / L;
        short8 p0 = *(const short8*)&po[(b4 + 0) * 32 + dh0];
        short8 p1 = *(const short8*)&po[(b4 + 1) * 32 + dh0];
        short8 p2 = *(const short8*)&po[(b4 + 2) * 32 + dh0];
        short8 p3 = *(const short8*)&po[(b4 + 3) * 32 + dh0];
        float vch[8];
        #pragma unroll
        for (int i = 0; i < 8; ++i) {
            vch[i] = (bf2f((unsigned short)p0[i]) + bf2f((unsigned short)p1[i])
                    + bf2f((unsigned short)p2[i]) + bf2f((unsigned short)p3[i])) * rcpL;
        }
        short8 a;
        #pragma unroll
        for (int i = 0; i < 4; ++i) {
            unsigned pk = cvt_pk_bf16(vch[2*i], vch[2*i+1]);
            a[2*i]   = (short)(pk & 0xFFFF);
            a[2*i+1] = (short)(pk >> 16);
        }
        #pragma unroll
        for (int nt = 0; nt < 2; ++nt) {
            short8 b = *(const short8*)(bp + (size_t)nt * 16 * K + k0);
            acc[nt] = __builtin_amdgcn_mfma_f32_16x16x32_bf16(a, b, acc[nt], 0, 0, 0);
        }
    }
    #pragma unroll
    for (int nt = 0; nt < 2; ++nt) {
        const int col = n0 + nt * 16 + ql;
        const float bv = bias[col];
        #pragma unroll
        for (int i = 0; i < 4; ++i) {
            int r = m0w + g * 4 + i;
            float v = acc[nt][i] + bv + addsrc[(size_t)r * HDIM + col];
            Cb[(size_t)r * HDIM + col] = bfr(v);
        }
    }
}

// ---------------------------------------------------------------------------
// attention softmax (per 16-q wave), no running max: p = exp2(s) directly.
__device__ inline void softmax_16q(f32x4 st[4], float& l,
        unsigned short* prow, int g) {
    float ll = 0.f;
    #pragma unroll
    for (int t = 0; t < 4; ++t) {
        float p0 = ex2(st[t][0]);
        float p1 = ex2(st[t][1]);
        float p2 = ex2(st[t][2]);
        float p3 = ex2(st[t][3]);
        ll += (p0 + p1) + (p2 + p3);
        uint2 w2; w2.x = cvt_pk_bf16(p0, p1); w2.y = cvt_pk_bf16(p2, p3);
        *(uint2*)&prow[t * 16 + g * 4] = w2;
    }
    ll += __shfl_xor(ll, 16);
    ll += __shfl_xor(ll, 32);
    l += ll;
}

// MFMA flash attention, split-K=4, flat grid, head = bid&7 (XCD affinity).
// K+V tiles staged through LDS, double-buffered, 1 barrier/iter (46us floor).
__global__ __launch_bounds__(256, 4) void k_attn_mfma(const unsigned short* __restrict__ qh,
        const unsigned short* __restrict__ kh, const unsigned short* __restrict__ vt,
        unsigned short* __restrict__ po, float* __restrict__ pl) {
    const int bid = blockIdx.x;
    const int hd = bid & 7;
    const int z  = (bid >> 3) & (SPLIT - 1);
    const int qb = bid >> 5;
    const int tid = threadIdx.x;
    const int wave = tid >> 6, lane = tid & 63;
    const int ql = lane & 15, g = lane >> 4;

    __shared__ unsigned short Klds[2][64 * 40];
    __shared__ unsigned short Vt[2][32 * 72];
    __shared__ unsigned short Plds[4][16 * 72];

    const unsigned short* khh = kh + (size_t)hd * NNODE * 32;
    const unsigned short* vtt = vt + (size_t)hd * 32 * NNODE;
    const int row = qb * 64 + wave * 16 + ql;
    short8 qf = *(const short8*)(qh + ((size_t)hd * NNODE + row) * 32 + g * 8);

    f32x4 oa0 = {0,0,0,0}, oa1 = {0,0,0,0};
    float l = 0.f;

    const int skey = tid >> 2, skc = (tid & 3) * 8;
    const int sdh = tid >> 3, sch = (tid & 7) * 8;
    const unsigned short* ksrc = khh + (size_t)skey * 32 + skc;
    const unsigned short* vsrc = vtt + (size_t)sdh * NNODE + sch;
    unsigned short* prow = &Plds[wave][ql * 72];
    const int TPS = NNODE / 64 / SPLIT;
    const int t0 = z * TPS;

    {
        short8 kv = *(const short8*)(ksrc + (size_t)t0 * 64 * 32);
        short8 vv = *(const short8*)(vsrc + t0 * 64);
        *(short8*)&Klds[0][skey * 40 + skc] = kv;
        *(short8*)&Vt[0][sdh * 72 + sch] = vv;
    }
    __syncthreads();
    int cur = 0;

    for (int kt = t0; kt < t0 + TPS; ++kt) {
        short8 kv, vv;
        const bool pref = (kt + 1 < t0 + TPS);
        if (pref) {
            kv = *(const short8*)(ksrc + (size_t)(kt + 1) * 64 * 32);
            vv = *(const short8*)(vsrc + (kt + 1) * 64);
        }

        f32x4 st[4];
        __builtin_amdgcn_s_setprio(1);
        #pragma unroll
        for (int t = 0; t < 4; ++t) {
            short8 kf = *(const short8*)&Klds[cur][(t * 16 + ql) * 40 + g * 8];
            st[t] = __builtin_amdgcn_mfma_f32_16x16x32_bf16(kf, qf, (f32x4){0,0,0,0}, 0, 0, 0);
        }
        __builtin_amdgcn_s_setprio(0);

        softmax_16q(st, l, prow, g);

        if (pref) {
            *(short8*)&Klds[cur ^ 1][skey * 40 + skc] = kv;
            *(short8*)&Vt[cur ^ 1][sdh * 72 + sch] = vv;
        }

        __builtin_amdgcn_s_setprio(1);
        #pragma unroll
        for (int c = 0; c < 2; ++c) {
            short8 pf = *(const short8*)&prow[c * 32 + g * 8];
            short8 v0 = *(const short8*)&Vt[cur][ql * 72 + c * 32 + g * 8];
            short8 v1 = *(const short8*)&Vt[cur][(16 + ql) * 72 + c * 32 + g * 8];
            oa0 = __builtin_amdgcn_mfma_f32_16x16x32_bf16(v0, pf, oa0, 0, 0, 0);
            oa1 = __builtin_amdgcn_mfma_f32_16x16x32_bf16(v1, pf, oa1, 0, 0, 0);
        }
        __builtin_amdgcn_s_setprio(0);

        __syncthreads();
        cur ^= 1;
    }

    const size_t pidx = ((size_t)hd * NNODE + row) * SPLIT + z;
    unsigned short* pp = po + pidx * 32;
    uint2 r;
    r.x = cvt_pk_bf16(oa0[0], oa0[1]); r.y = cvt_pk_bf16(oa0[2], oa0[3]);
    *(uint2*)&pp[g * 4] = r;
    r.x = cvt_pk_bf16(oa1[0], oa1[1]); r.y = cvt_pk_bf16(oa1[2], oa1[3]);
    *(uint2*)&pp[16 + g * 4] = r;
    if (g == 0) pl[pidx] = l;
}

// ---------------------------------------------------------------------------
// heads layer-2 epilogue: one wave per node; th = [4096][256] pre-relu fp32.
__global__ __launch_bounds__(256) void k_heads2(const float* __restrict__ th,
        const float* __restrict__ fp2w, const float* __restrict__ fp2b,
        const float* __restrict__ pd2w, const float* __restrict__ pd2b,
        float* __restrict__ out) {
    const int wave = threadIdx.x >> 6, lane = threadIdx.x & 63;
    const int n = blockIdx.x * 4 + wave;
    const int half = lane >> 5;
    const int li = lane & 31;
    float4 h4 = *(const float4*)&th[(size_t)n * HDIM + half * 128 + li * 4];
    h4.x = fmaxf(h4.x, 0.f); h4.y = fmaxf(h4.y, 0.f);
    h4.z = fmaxf(h4.z, 0.f); h4.w = fmaxf(h4.w, 0.f);
    float lf[3];
    float lp[10];
    #pragma unroll
    for (int j = 0; j < 10; ++j) {
        float partial = 0.f;
        if (half == 0) {
            if (j < 3) {
                float4 wv = *(const float4*)&fp2w[j * 128 + li * 4];
                partial = h4.x*wv.x + h4.y*wv.y + h4.z*wv.z + h4.w*wv.w;
            }
        } else {
            float4 wv = *(const float4*)&pd2w[j * 128 + li * 4];
            partial = h4.x*wv.x + h4.y*wv.y + h4.z*wv.z + h4.w*wv.w;
        }
        #pragma unroll
        for (int d = 1; d < 32; d <<= 1) partial += __shfl_xor(partial, d);
        if (j < 3) lf[j] = partial;
        lp[j] = partial;
    }
    if (lane == 0) {
        float l0 = lf[0] + fp2b[0], l1 = lf[1] + fp2b[1], l2 = lf[2] + fp2b[2];
        float mx = fmaxf(l0, fmaxf(l1, l2));
        float e0 = __expf(l0 - mx), e1 = __expf(l1 - mx), e2 = __expf(l2 - mx);
        float inv = 1.f / (e0 + e1 + e2);
        out[(size_t)n * 3 + 0] = e0 * inv;
        out[(size_t)n * 3 + 1] = e1 * inv;
        out[(size_t)n * 3 + 2] = e2 * inv;
    } else if (lane == 32) {
        #pragma unroll
        for (int j = 0; j < 10; ++j)
            out[(size_t)NNODE * 3 + (size_t)n * 10 + j] =
                1.f / (1.f + __expf(-(lp[j] + pd2b[j])));
    }
}

// ---------------------------------------------------------------------------
extern "C" void kernel_launch(void* const* d_in, const int* in_sizes, int n_in,
                              void* d_out, int out_size, void* d_ws, size_t ws_size,
                              hipStream_t stream) {
    const float* x    = (const float*)d_in[0];
    const int*   ei   = (const int*)  d_in[1];
    const float* W1   = (const float*)d_in[2];
    const float* b1   = (const float*)d_in[3];
    const float* W2   = (const float*)d_in[4];
    const float* b2   = (const float*)d_in[5];
    const float* W3   = (const float*)d_in[6];
    const float* b3   = (const float*)d_in[7];
    const float* in_w = (const float*)d_in[8];
    const float* in_b = (const float*)d_in[9];
    const float* outw = (const float*)d_in[10];
    const float* outb = (const float*)d_in[11];
    const float* fp1w = (const float*)d_in[12];
    const float* fp1b = (const float*)d_in[13];
    const float* fp2w = (const float*)d_in[14];
    const float* fp2b = (const float*)d_in[15];
    const float* pd1w = (const float*)d_in[16];
    const float* pd1b = (const float*)d_in[17];
    const float* pd2w = (const float*)d_in[18];
    const float* pd2b = (const float*)d_in[19];
    float* out = (float*)d_out;

    const int E = in_sizes[1] / 2;

    char* w = (char*)d_ws;
    auto alloc = [&](size_t bytes) {
        char* p = w; w += (bytes + 255) & ~(size_t)255; return p;
    };
    int*   degi   = (int*)alloc(NNODE * 4);
    int*   off    = (int*)alloc(NNODE * 4);
    int*   cursor = (int*)alloc(NNODE * 4);
    int*   csr    = (int*)alloc((size_t)E * 4);
    float* dinv   = (float*)alloc(NNODE * 4);
    float* invdeg = (float*)alloc(NNODE * 4);
    unsigned short* W1t   = (unsigned short*)alloc(256 * 128 * 2);
    unsigned short* W2t   = (unsigned short*)alloc(256 * 256 * 2);
    unsigned short* W3t   = (unsigned short*)alloc(256 * 256 * 2);
    unsigned short* in_wb = (unsigned short*)alloc(768 * 256 * 2);
    unsigned short* outwb = (unsigned short*)alloc(256 * 256 * 2);
    unsigned short* wcatb = (unsigned short*)alloc(256 * 256 * 2);
    float* bcat  = (float*)alloc(256 * 4);
    unsigned short* xb    = (unsigned short*)alloc((size_t)NNODE * DIN * 2);
    unsigned short* g1b   = (unsigned short*)alloc((size_t)NNODE * DIN * 2);
    float* bufA  = (float*)alloc((size_t)NNODE * HDIM * 4);
    unsigned short* h1b   = (unsigned short*)alloc((size_t)NNODE * HDIM * 2);
    unsigned short* g2b   = (unsigned short*)alloc((size_t)NNODE * HDIM * 2);
    unsigned short* h2b   = (unsigned short*)alloc((size_t)NNODE * HDIM * 2);
    unsigned short* g3b   = (unsigned short*)alloc((size_t)NNODE * HDIM * 2);
    float* hf    = (float*)alloc((size_t)NNODE * HDIM * 4);
    unsigned short* hb    = (unsigned short*)alloc((size_t)NNODE * HDIM * 2);
    unsigned short* qh    = (unsigned short*)alloc((size_t)HEADS * NNODE * 32 * 2);
    unsigned short* kh    = (unsigned short*)alloc((size_t)HEADS * NNODE * 32 * 2);
    unsigned short* vt    = (unsigned short*)alloc((size_t)HEADS * 32 * NNODE * 2);
    unsigned short* po    = (unsigned short*)alloc((size_t)HEADS * NNODE * SPLIT * 32 * 2);
    float* pl    = (float*)alloc((size_t)HEADS * NNODE * SPLIT * 4);
    unsigned short* hfinb = (unsigned short*)alloc((size_t)NNODE * HDIM * 2);

    // CSR + prep (deg fused into prep; degi zeroed by async memset)
    hipMemsetAsync(degi, 0, NNODE * sizeof(int), stream);
    const int prep_slots = 557056 + E;
    k_prep<<<(prep_slots + 255) / 256, 256, 0, stream>>>(
        W1, W2, W3, in_w, outw, fp1w, pd1w, fp1b, pd1b, x, ei, E, degi,
        W1t, W2t, W3t, in_wb, outwb, wcatb, bcat, xb);
    k_scan_norm<<<1, 256, 0, stream>>>(degi, off, cursor, dinv, invdeg);
    k_fill<<<(E + 255) / 256, 256, 0, stream>>>(ei, cursor, csr, E);

    dim3 g256(HDIM / 32, NNODE / 64);   // (8,64)
    dim3 g768(768 / 32, NNODE / 64);    // (24,64)

    // conv1 (gather-first by linearity): g1 = gather(xb); h1 = relu(g1@W1+b1)
    k_gather2<2><<<NNODE / 4, 256, 0, stream>>>(xb, csr, off, degi, dinv, invdeg, g1b);
    k_bgemm<DIN, 3, true, false><<<g256, 256, 0, stream>>>(g1b, W1t, b1, nullptr, h1b, nullptr, nullptr, HDIM);
    // conv2
    k_gather2<4><<<NNODE / 4, 256, 0, stream>>>(h1b, csr, off, degi, dinv, invdeg, g2b);
    k_bgemm<HDIM, 3, true, false><<<g256, 256, 0, stream>>>(g2b, W2t, b2, nullptr, h2b, nullptr, nullptr, HDIM);
    // conv3 (dual output: bf16 hb + fp32 hf residual)
    k_gather2<4><<<NNODE / 4, 256, 0, stream>>>(h2b, csr, off, degi, dinv, invdeg, g3b);
    k_bgemm<HDIM, 4, true, false><<<g256, 256, 0, stream>>>(g3b, W3t, b3, nullptr, hb, hf, nullptr, HDIM);

    // MHA: qkv GEMM (q,k head-major; V transposed), attention, fused merge+out-proj
    k_bgemm<HDIM, 2, true, false><<<g768, 256, 0, stream>>>(hb, in_wb, in_b, nullptr, qh, kh, vt, 768);
    k_attn_mfma<<<HEADS * SPLIT * (NNODE / 64), 256, 0, stream>>>(qh, kh, vt, po, pl);
    k_bgemm_merge<<<g256, 256, 0, stream>>>(po, pl, outwb, outb, hf, hfinb);

    // MLP heads
    k_bgemm<HDIM, 0, true, false><<<g256, 256, 0, stream>>>(hfinb, wcatb, bcat, nullptr, bufA, nullptr, nullptr, HDIM);
    k_heads2<<<NNODE / 4, 256, 0, stream>>>(bufA, fp2w, fp2b, pd2w, pd2b, out);
}